// Round 19
// baseline (191.144 us; speedup 1.0000x reference)
//
#include <hip/hip_runtime.h>

typedef unsigned short u16;
typedef __attribute__((ext_vector_type(8))) short bf16x8;
typedef __attribute__((ext_vector_type(4))) float f32x4;

#define BK 64
#define TM 2
#define BM 64

__device__ __forceinline__ u16 f2bf(float f) {
    unsigned u = __float_as_uint(f);
    unsigned r = u + 0x7fffu + ((u >> 16) & 1u);
    return (u16)(r >> 16);
}
__device__ __forceinline__ float bf2f(u16 h) {
    return __uint_as_float(((unsigned)h) << 16);
}

__device__ __forceinline__ void gload_lds16(const u16* g, u16* l) {
    __builtin_amdgcn_global_load_lds(
        (__attribute__((address_space(1))) unsigned int*)(u16*)g,
        (__attribute__((address_space(3))) unsigned int*)l,
        16, 0, 0);
}

// ---------- fused input conversion + rowsum zeroing ----------
__global__ __launch_bounds__(256) void cvt_in_kernel(const float* __restrict__ x,
                                                     const float* __restrict__ W,
                                                     u16* __restrict__ xb,
                                                     u16* __restrict__ Wt,
                                                     float* __restrict__ rsum) {
    const int bid = blockIdx.x;
    const int tid = threadIdx.x;
    if (bid < 6144) {
        int i = bid * 256 + tid;
        float4 f = ((const float4*)x)[i];
        ushort4 u;
        u.x = f2bf(f.x); u.y = f2bf(f.y); u.z = f2bf(f.z); u.w = f2bf(f.w);
        ((ushort4*)xb)[i] = u;
    } else if (bid < 7872) {
        __shared__ float t[32][33];
        const int b = bid - 6144;
        const int j = b / 576;
        const int rem = b - j * 576;
        const int d0 = (rem % 24) * 32, o0 = (rem / 24) * 32;
        const int tx = tid & 31, ty = tid >> 5;
#pragma unroll
        for (int i = 0; i < 4; i++) {
            int d = d0 + ty + i * 8;
            t[ty + i * 8][tx] = W[((long)j * 768 + d) * 768 + o0 + tx];
        }
        __syncthreads();
#pragma unroll
        for (int i = 0; i < 4; i++) {
            int o = o0 + ty + i * 8;
            Wt[((long)j * 768 + o) * 768 + d0 + tx] = f2bf(t[tx][ty + i * 8]);
        }
    } else {
        const float4 z4 = {0.f, 0.f, 0.f, 0.f};
#pragma unroll
        for (int j = 0; j < 8; j++) ((float4*)rsum)[tid * 8 + j] = z4;
    }
}

// ---------- QKV: 128x128 tile, DOUBLE-buffer counted-vmcnt ----------
// stage(t+1); vmcnt(8) [wait-for-oldest: stage-t retired, t+1 in flight];
// raw s_barrier; bulk compute(t); s_barrier. NEVER vmcnt(0) in main loop.
// Direct Q/K stores; V transposed via LDS.
__device__ __forceinline__ void stage128(const u16* Ab, const u16* Bb, int k0,
                                         u16* p, int wave, int rl, int pc) {
    u16* As = p;
    u16* Bs = p + 8192;
#pragma unroll
    for (int t = 0; t < 4; ++t) {
        const int g = wave + t * 4;          // wave-uniform 0..15
        const int row = g * 8 + rl;
        const int gc = pc ^ (row & 7);
        gload_lds16(Ab + (long)row * 768 + k0 + gc * 8, &As[g * 512]);
    }
#pragma unroll
    for (int t = 0; t < 4; ++t) {
        const int g = wave + t * 4;
        const int row = g * 8 + rl;
        const int gc = pc ^ (row & 7);
        gload_lds16(Bb + (long)row * 768 + k0 + gc * 8, &Bs[g * 512]);
    }
}

__global__ __launch_bounds__(256, 2)
void qkv_kernel(const u16* __restrict__ xb, const u16* __restrict__ Wt,
                u16* __restrict__ o16, u16* __restrict__ vt) {
    constexpr int BUF = 16384;                           // 2 x 8192 u16 (A|B)
    __shared__ __align__(16) u16 smem[2 * BUF];          // 65536 B

    const int nb = gridDim.x;            // 1152
    const int chunk = nb >> 3;           // 144
    const int nl = (blockIdx.x & 7) * chunk + (blockIdx.x >> 3);
    const int bx = nl / 18;
    const int by = nl - bx * 18;

    const int tid = threadIdx.x;
    const int lane = tid & 63;
    const int wave = tid >> 6;

    const u16* Ab = xb + (long)bx * 128 * 768;
    const u16* Bb = Wt + (long)by * 128 * 768;

    const int rl = lane >> 3;
    const int pc = lane & 7;
    const int q = lane >> 4;
    const int rA = lane & 15;
    const int wm = (wave >> 1) * 64;
    const int wn = (wave & 1) * 64;

    f32x4 acc[4][4];
    const f32x4 zero = {0.f, 0.f, 0.f, 0.f};
#pragma unroll
    for (int i = 0; i < 4; i++)
#pragma unroll
        for (int j = 0; j < 4; j++) acc[i][j] = zero;

    u16* p0 = smem;
    u16* p1 = smem + BUF;

    stage128(Ab, Bb, 0, p0, wave, rl, pc);
    for (int t = 0; t < 12; ++t) {
        u16* cur = (t & 1) ? p1 : p0;
        u16* nxt = (t & 1) ? p0 : p1;
        if (t + 1 < 12) {
            stage128(Ab, Bb, (t + 1) * BK, nxt, wave, rl, pc);
            asm volatile("s_waitcnt vmcnt(8)" ::: "memory");   // stage t done
        } else {
            asm volatile("s_waitcnt vmcnt(0)" ::: "memory");
        }
        __builtin_amdgcn_sched_barrier(0);
        __builtin_amdgcn_s_barrier();
        {
            const u16* As = cur;
            const u16* Bs = cur + 8192;
            __builtin_amdgcn_s_setprio(1);
#pragma unroll
            for (int kk = 0; kk < BK; kk += 32) {
                const int gchunk = (kk >> 3) + q;
                bf16x8 af[4], bfr[4];
#pragma unroll
                for (int mi = 0; mi < 4; ++mi) {
                    const int R = wm + mi * 16 + rA;
                    af[mi] = *(const bf16x8*)&As[R * 64 + ((gchunk ^ (R & 7)) << 3)];
                }
#pragma unroll
                for (int ni = 0; ni < 4; ++ni) {
                    const int R = wn + ni * 16 + rA;
                    bfr[ni] = *(const bf16x8*)&Bs[R * 64 + ((gchunk ^ (R & 7)) << 3)];
                }
#pragma unroll
                for (int mi = 0; mi < 4; ++mi)
#pragma unroll
                    for (int ni = 0; ni < 4; ++ni)
                        acc[mi][ni] = __builtin_amdgcn_mfma_f32_16x16x32_bf16(
                            af[mi], bfr[ni], acc[mi][ni], 0, 0, 0);
            }
            __builtin_amdgcn_s_setprio(0);
        }
        __builtin_amdgcn_s_barrier();
    }

    const int rowb = bx * 128 + wm + q * 4;
    const int colb = by * 128 + wn + rA;

    if (by >= 12) {
        // V -> Vt[b][o][s] via LDS tile [128 o][136 pad s]
        u16* T = smem;
#pragma unroll
        for (int mi = 0; mi < 4; ++mi)
#pragma unroll
            for (int ni = 0; ni < 4; ++ni) {
                const int lc = wn + ni * 16 + rA;
#pragma unroll
                for (int r = 0; r < 4; ++r) {
                    const int lr = wm + mi * 16 + q * 4 + r;
                    T[lc * 136 + lr] = f2bf(acc[mi][ni][r]);
                }
            }
        __syncthreads();
        const int b = bx >> 4;               // 16 x-blocks per batch
        const int s0 = (bx & 15) * 128;
        const int o0 = (by - 12) * 128;
        const int ol = tid >> 1, h = (tid & 1) * 64;
        u16* dst = vt + ((long)b * 768 + o0 + ol) * 2048 + s0 + h;
        const u16* src = &T[ol * 136 + h];
#pragma unroll
        for (int j = 0; j < 8; ++j)
            *(uint4*)(dst + j * 8) = *(const uint4*)(src + j * 8);
        return;
    }

    const int seg = by / 6;                  // 0=Q, 1=K
    const int ocol = colb - seg * 768;
#pragma unroll
    for (int mi = 0; mi < 4; ++mi)
#pragma unroll
        for (int ni = 0; ni < 4; ++ni)
#pragma unroll
            for (int r = 0; r < 4; ++r)
                o16[(long)seg * 6291456 + (long)(rowb + mi * 16 + r) * 768 +
                    ocol + ni * 16] = f2bf(acc[mi][ni][r]);
}

// ---------- shared helpers for bf16 64x128 tiles (PV) ----------
__device__ __forceinline__ void stage_tiles(const u16* Ab, const u16* Bb, int K,
                                            int k0, u16* p, int wave, int rl,
                                            int pc) {
    u16* As = p;
    u16* Bs = p + BM * BK;
#pragma unroll
    for (int t = 0; t < TM; ++t) {
        const int issue = wave + t * 4;
        const int row = issue * 8 + rl;
        const int gc = pc ^ (row & 7);
        gload_lds16(Ab + (long)row * K + k0 + gc * 8, &As[issue * 512]);
    }
#pragma unroll
    for (int t = 0; t < 4; ++t) {
        const int issue = wave + t * 4;
        const int row = issue * 8 + rl;
        const int gc = pc ^ (row & 7);
        gload_lds16(Bb + (long)row * K + k0 + gc * 8, &Bs[issue * 512]);
    }
}

__device__ __forceinline__ void compute_tile(const u16* p, f32x4 (&acc)[TM][4],
                                             int wm, int wn, int q, int rA) {
    const u16* As = p;
    const u16* Bs = p + BM * BK;
#pragma unroll
    for (int kk = 0; kk < BK; kk += 32) {
        const int gchunk = (kk >> 3) + q;
        bf16x8 af[TM], bfr[4];
#pragma unroll
        for (int mi = 0; mi < TM; ++mi) {
            const int R = wm + mi * 16 + rA;
            af[mi] = *(const bf16x8*)&As[R * 64 + ((gchunk ^ (R & 7)) << 3)];
        }
#pragma unroll
        for (int ni = 0; ni < 4; ++ni) {
            const int R = wn + ni * 16 + rA;
            bfr[ni] = *(const bf16x8*)&Bs[R * 64 + ((gchunk ^ (R & 7)) << 3)];
        }
#pragma unroll
        for (int mi = 0; mi < TM; ++mi)
#pragma unroll
            for (int ni = 0; ni < 4; ++ni)
                acc[mi][ni] = __builtin_amdgcn_mfma_f32_16x16x32_bf16(
                    af[mi], bfr[ni], acc[mi][ni], 0, 0, 0);
    }
}

// ---------- PV: 64x128, TRIPLE-buffer counted-vmcnt (K=2048, 32 tiles) -------
__global__ __launch_bounds__(256)
void pv_kernel(const u16* __restrict__ Sb, const u16* __restrict__ Vt,
               float* __restrict__ out, const float* __restrict__ rsum) {
    constexpr int BUF = BM * BK + 128 * BK;              // 12288 u16
    __shared__ __align__(16) u16 smem[3 * BUF];          // 73728 B

    const int nb = gridDim.x;            // 768
    const int chunk = nb >> 3;
    const int nl = (blockIdx.x & 7) * chunk + (blockIdx.x >> 3);
    const int bz = nl / 192;
    const int rem = nl - bz * 192;
    const int bx = rem / 6;
    const int by = rem - bx * 6;

    const int tid = threadIdx.x;
    const int lane = tid & 63;
    const int wave = tid >> 6;

    const u16* Ab = Sb + (long)bz * 4194304L + (long)bx * BM * 2048;
    const u16* Bb = Vt + (long)bz * 1572864L + (long)by * 128 * 2048;

    const int rl = lane >> 3;
    const int pc = lane & 7;
    const int q = lane >> 4;
    const int rA = lane & 15;
    const int wm = (wave >> 1) * 32;
    const int wn = (wave & 1) * 64;

    f32x4 acc[TM][4];
    const f32x4 zero = {0.f, 0.f, 0.f, 0.f};
#pragma unroll
    for (int i = 0; i < TM; i++)
#pragma unroll
        for (int j = 0; j < 4; j++) acc[i][j] = zero;

    u16* p0 = smem;
    u16* p1 = smem + BUF;
    u16* p2 = smem + 2 * BUF;

    const int NT = 32;
    stage_tiles(Ab, Bb, 2048, 0, p0, wave, rl, pc);
    stage_tiles(Ab, Bb, 2048, BK, p1, wave, rl, pc);
    for (int t = 0; t < NT; ++t) {
        if (t + 2 < NT) {
            stage_tiles(Ab, Bb, 2048, (t + 2) * BK, p2, wave, rl, pc);
            asm volatile("s_waitcnt vmcnt(12)" ::: "memory");
        } else if (t + 1 < NT) {
            asm volatile("s_waitcnt vmcnt(6)" ::: "memory");
        } else {
            asm volatile("s_waitcnt vmcnt(0)" ::: "memory");
        }
        __builtin_amdgcn_sched_barrier(0);
        __builtin_amdgcn_s_barrier();
        compute_tile(p0, acc, wm, wn, q, rA);
        __builtin_amdgcn_s_barrier();
        u16* tmp = p0; p0 = p1; p1 = p2; p2 = tmp;
    }

    const int rowb = bx * BM + wm + q * 4;
    const int colb = by * 128 + wn + rA;
    float* dst = out + (long)bz * 1572864L;
#pragma unroll
    for (int mi = 0; mi < TM; ++mi) {
        const float4 rs4 = *(const float4*)&rsum[bz * 2048 + rowb + mi * 16];
        const float inv[4] = {1.f / rs4.x, 1.f / rs4.y, 1.f / rs4.z, 1.f / rs4.w};
#pragma unroll
        for (int ni = 0; ni < 4; ++ni)
#pragma unroll
            for (int r = 0; r < 4; ++r)
                dst[(long)(rowb + mi * 16 + r) * 768 + colb + ni * 16] =
                    acc[mi][ni][r] * inv[r];
    }
}

// ---------- scores: 256x256 tile, 8 waves, counted-vmcnt double-buffer -------
// (Triple-buffer does NOT fit: 3 x 64KB tiles = 192KB > 160KB LDS — round 15.)
__device__ __forceinline__ void sc_stage(const u16* Ab, const u16* Bb, u16* A_,
                                         int t, int w, int rl, int pc) {
    const int k0 = t * 64;
    u16* B_ = A_ + 16384;
#pragma unroll
    for (int j = 0; j < 4; ++j) {
        const int g = w + j * 8;              // wave-uniform, 0..31
        const int row = g * 8 + rl;
        const int gc = pc ^ (row & 7);
        gload_lds16(Ab + (long)row * 768 + k0 + gc * 8, &A_[g * 512]);
    }
#pragma unroll
    for (int j = 0; j < 4; ++j) {
        const int g = w + j * 8;
        const int row = g * 8 + rl;
        const int gc = pc ^ (row & 7);
        gload_lds16(Bb + (long)row * 768 + k0 + gc * 8, &B_[g * 512]);
    }
}

__device__ __forceinline__ void sc_comp(const u16* A_, f32x4 (&acc)[8][4],
                                        int wm, int wn, int q, int rA) {
    const u16* B_ = A_ + 16384;
    __builtin_amdgcn_s_setprio(1);
#pragma unroll
    for (int kk = 0; kk < 64; kk += 32) {
        const int gchunk = (kk >> 3) + q;
        bf16x8 bfr[4];
#pragma unroll
        for (int ni = 0; ni < 4; ++ni) {
            const int R = wn + ni * 16 + rA;
            bfr[ni] = *(const bf16x8*)&B_[R * 64 + ((gchunk ^ (R & 7)) << 3)];
        }
#pragma unroll
        for (int mi = 0; mi < 8; ++mi) {
            const int R = wm + mi * 16 + rA;
            const bf16x8 af = *(const bf16x8*)&A_[R * 64 + ((gchunk ^ (R & 7)) << 3)];
#pragma unroll
            for (int ni = 0; ni < 4; ++ni)
                acc[mi][ni] = __builtin_amdgcn_mfma_f32_16x16x32_bf16(
                    af, bfr[ni], acc[mi][ni], 0, 0, 0);
        }
    }
    __builtin_amdgcn_s_setprio(0);
}

__global__ __launch_bounds__(512, 2)
void scores256_kernel(const u16* __restrict__ Q, const u16* __restrict__ Kb,
                      u16* __restrict__ Sb, float* __restrict__ rsum) {
    __shared__ __align__(16) u16 smem[65536];   // 128 KiB

    const int nb = gridDim.x;                   // 256
    const int chunk = nb >> 3;
    const int nl = (blockIdx.x & 7) * chunk + (blockIdx.x >> 3);
    const int bz = nl >> 6;
    const int rem = nl & 63;
    const int bx = rem >> 3;
    const int by = rem & 7;

    const int tid = threadIdx.x;
    const int lane = tid & 63;
    const int w = tid >> 6;

    const u16* Ab = Q + (long)bz * 1572864L + (long)bx * 256 * 768;
    const u16* Bb = Kb + (long)bz * 1572864L + (long)by * 256 * 768;

    const int rl = lane >> 3, pc = lane & 7;
    const int q = lane >> 4, rA = lane & 15;
    const int wm = (w >> 2) * 128, wn = (w & 3) * 64;

    f32x4 acc[8][4];
    const f32x4 zero = {0.f, 0.f, 0.f, 0.f};
#pragma unroll
    for (int i = 0; i < 8; i++)
#pragma unroll
        for (int j = 0; j < 4; j++) acc[i][j] = zero;

    u16* buf0 = smem;
    u16* buf1 = smem + 32768;

    sc_stage(Ab, Bb, buf0, 0, w, rl, pc);
    for (int i = 0; i < 6; ++i) {
        sc_stage(Ab, Bb, buf1, 2 * i + 1, w, rl, pc);
        asm volatile("s_waitcnt vmcnt(8)" ::: "memory");
        __builtin_amdgcn_sched_barrier(0);
        __builtin_amdgcn_s_barrier();
        sc_comp(buf0, acc, wm, wn, q, rA);
        __builtin_amdgcn_s_barrier();
        if (2 * i + 2 < 12) {
            sc_stage(Ab, Bb, buf0, 2 * i + 2, w, rl, pc);
            asm volatile("s_waitcnt vmcnt(8)" ::: "memory");
        } else {
            asm volatile("s_waitcnt vmcnt(0)" ::: "memory");
        }
        __builtin_amdgcn_sched_barrier(0);
        __builtin_amdgcn_s_barrier();
        sc_comp(buf1, acc, wm, wn, q, rA);
        __builtin_amdgcn_s_barrier();
    }

    const int rowb = bx * 256 + wm + q * 4;
    const int colb = by * 256 + wn + rA;
    u16* dst = Sb + (long)bz * 4194304L;
    const float scale = 0.057735026918962574f;
#pragma unroll
    for (int mi = 0; mi < 8; ++mi) {
        float rs[4] = {0.f, 0.f, 0.f, 0.f};
#pragma unroll
        for (int ni = 0; ni < 4; ++ni)
#pragma unroll
            for (int r = 0; r < 4; ++r) {
                const float p = __expf(acc[mi][ni][r] * scale);
                const u16 pb = f2bf(p);
                dst[(long)(rowb + mi * 16 + r) * 2048 + colb + ni * 16] = pb;
                rs[r] += bf2f(pb);
            }
#pragma unroll
        for (int r = 0; r < 4; ++r) {
#pragma unroll
            for (int off = 1; off <= 8; off <<= 1) rs[r] += __shfl_xor(rs[r], off);
            if (rA == 0)
                atomicAdd(&rsum[bz * 2048 + rowb + mi * 16 + r], rs[r]);
        }
    }
}

extern "C" void kernel_launch(void* const* d_in, const int* in_sizes, int n_in,
                              void* d_out, int out_size, void* d_ws, size_t ws_size,
                              hipStream_t stream) {
    const float* x = (const float*)d_in[0];     // [4,2048,768]
    const float* w = (const float*)d_in[1];     // [3,768,768]
    float* out = (float*)d_out;                 // [4,2048,768]

    const long NX = 6291456L;   // 4*2048*768
    const long NS = 16777216L;  // 4*2048*2048

    u16* Sb = (u16*)d_ws;
    u16* xb = Sb;                 // NX (overlay, dead before scores writes Sb)
    u16* wt = Sb + NX;            // 1769472  (< NS)
    u16* Qb = Sb + NS;
    u16* Kb = Qb + NX;
    u16* Vt = Kb + NX;
    float* rowsum = (float*)(Vt + NX);

    // 1. x -> bf16; W -> Wt[2304][768] bf16 transposed; rowsum <- 0
    cvt_in_kernel<<<7873, 256, 0, stream>>>(x, w, xb, wt, rowsum);
    // 2. QKV: 128x128 counted-vmcnt dbuf; Q,K direct; V transposed into Vt
    qkv_kernel<<<1152, 256, 0, stream>>>(xb, wt, Qb, Vt);
    // 3. P~ = exp(QK^T/sqrt(300)) bf16 -> Sb, + rowsum atomics
    scores256_kernel<<<256, 512, 0, stream>>>(Qb, Kb, Sb, rowsum);
    // 4. out = (P~ x Vt^T) / rowsum -> fp32 (triple-buffer counted-vmcnt)
    pv_kernel<<<768, 256, 0, stream>>>(Sb, Vt, out, rowsum);
}

// Round 20
// 180.823 us; speedup vs baseline: 1.0571x; 1.0571x over previous
//
#include <hip/hip_runtime.h>

typedef unsigned short u16;
typedef __attribute__((ext_vector_type(8))) short bf16x8;
typedef __attribute__((ext_vector_type(4))) float f32x4;

#define BK 64
#define TM 2
#define BM 64

__device__ __forceinline__ u16 f2bf(float f) {
    unsigned u = __float_as_uint(f);
    unsigned r = u + 0x7fffu + ((u >> 16) & 1u);
    return (u16)(r >> 16);
}
__device__ __forceinline__ float bf2f(u16 h) {
    return __uint_as_float(((unsigned)h) << 16);
}

__device__ __forceinline__ void gload_lds16(const u16* g, u16* l) {
    __builtin_amdgcn_global_load_lds(
        (__attribute__((address_space(1))) unsigned int*)(u16*)g,
        (__attribute__((address_space(3))) unsigned int*)l,
        16, 0, 0);
}

// ---------- fused input conversion + rowsum zeroing ----------
__global__ __launch_bounds__(256) void cvt_in_kernel(const float* __restrict__ x,
                                                     const float* __restrict__ W,
                                                     u16* __restrict__ xb,
                                                     u16* __restrict__ Wt,
                                                     float* __restrict__ rsum) {
    const int bid = blockIdx.x;
    const int tid = threadIdx.x;
    if (bid < 6144) {
        int i = bid * 256 + tid;
        float4 f = ((const float4*)x)[i];
        ushort4 u;
        u.x = f2bf(f.x); u.y = f2bf(f.y); u.z = f2bf(f.z); u.w = f2bf(f.w);
        ((ushort4*)xb)[i] = u;
    } else if (bid < 7872) {
        __shared__ float t[32][33];
        const int b = bid - 6144;
        const int j = b / 576;
        const int rem = b - j * 576;
        const int d0 = (rem % 24) * 32, o0 = (rem / 24) * 32;
        const int tx = tid & 31, ty = tid >> 5;
#pragma unroll
        for (int i = 0; i < 4; i++) {
            int d = d0 + ty + i * 8;
            t[ty + i * 8][tx] = W[((long)j * 768 + d) * 768 + o0 + tx];
        }
        __syncthreads();
#pragma unroll
        for (int i = 0; i < 4; i++) {
            int o = o0 + ty + i * 8;
            Wt[((long)j * 768 + o) * 768 + d0 + tx] = f2bf(t[tx][ty + i * 8]);
        }
    } else {
        const float4 z4 = {0.f, 0.f, 0.f, 0.f};
#pragma unroll
        for (int j = 0; j < 8; j++) ((float4*)rsum)[tid * 8 + j] = z4;
    }
}

// ---------- QKV: 128x128 tile, DOUBLE-buffer counted-vmcnt ----------
// stage(t+1); vmcnt(8) [wait-for-oldest: stage-t retired, t+1 in flight];
// raw s_barrier; bulk compute(t); s_barrier. NEVER vmcnt(0) in main loop.
// Direct Q/K stores; V transposed via LDS.
__device__ __forceinline__ void stage128(const u16* Ab, const u16* Bb, int k0,
                                         u16* p, int wave, int rl, int pc) {
    u16* As = p;
    u16* Bs = p + 8192;
#pragma unroll
    for (int t = 0; t < 4; ++t) {
        const int g = wave + t * 4;          // wave-uniform 0..15
        const int row = g * 8 + rl;
        const int gc = pc ^ (row & 7);
        gload_lds16(Ab + (long)row * 768 + k0 + gc * 8, &As[g * 512]);
    }
#pragma unroll
    for (int t = 0; t < 4; ++t) {
        const int g = wave + t * 4;
        const int row = g * 8 + rl;
        const int gc = pc ^ (row & 7);
        gload_lds16(Bb + (long)row * 768 + k0 + gc * 8, &Bs[g * 512]);
    }
}

__global__ __launch_bounds__(256, 2)
void qkv_kernel(const u16* __restrict__ xb, const u16* __restrict__ Wt,
                u16* __restrict__ o16, u16* __restrict__ vt) {
    constexpr int BUF = 16384;                           // 2 x 8192 u16 (A|B)
    __shared__ __align__(16) u16 smem[2 * BUF];          // 65536 B

    const int nb = gridDim.x;            // 1152
    const int chunk = nb >> 3;           // 144
    const int nl = (blockIdx.x & 7) * chunk + (blockIdx.x >> 3);
    const int bx = nl / 18;
    const int by = nl - bx * 18;

    const int tid = threadIdx.x;
    const int lane = tid & 63;
    const int wave = tid >> 6;

    const u16* Ab = xb + (long)bx * 128 * 768;
    const u16* Bb = Wt + (long)by * 128 * 768;

    const int rl = lane >> 3;
    const int pc = lane & 7;
    const int q = lane >> 4;
    const int rA = lane & 15;
    const int wm = (wave >> 1) * 64;
    const int wn = (wave & 1) * 64;

    f32x4 acc[4][4];
    const f32x4 zero = {0.f, 0.f, 0.f, 0.f};
#pragma unroll
    for (int i = 0; i < 4; i++)
#pragma unroll
        for (int j = 0; j < 4; j++) acc[i][j] = zero;

    u16* p0 = smem;
    u16* p1 = smem + BUF;

    stage128(Ab, Bb, 0, p0, wave, rl, pc);
    for (int t = 0; t < 12; ++t) {
        u16* cur = (t & 1) ? p1 : p0;
        u16* nxt = (t & 1) ? p0 : p1;
        if (t + 1 < 12) {
            stage128(Ab, Bb, (t + 1) * BK, nxt, wave, rl, pc);
            asm volatile("s_waitcnt vmcnt(8)" ::: "memory");   // stage t done
        } else {
            asm volatile("s_waitcnt vmcnt(0)" ::: "memory");
        }
        __builtin_amdgcn_sched_barrier(0);
        __builtin_amdgcn_s_barrier();
        {
            const u16* As = cur;
            const u16* Bs = cur + 8192;
            __builtin_amdgcn_s_setprio(1);
#pragma unroll
            for (int kk = 0; kk < BK; kk += 32) {
                const int gchunk = (kk >> 3) + q;
                bf16x8 af[4], bfr[4];
#pragma unroll
                for (int mi = 0; mi < 4; ++mi) {
                    const int R = wm + mi * 16 + rA;
                    af[mi] = *(const bf16x8*)&As[R * 64 + ((gchunk ^ (R & 7)) << 3)];
                }
#pragma unroll
                for (int ni = 0; ni < 4; ++ni) {
                    const int R = wn + ni * 16 + rA;
                    bfr[ni] = *(const bf16x8*)&Bs[R * 64 + ((gchunk ^ (R & 7)) << 3)];
                }
#pragma unroll
                for (int mi = 0; mi < 4; ++mi)
#pragma unroll
                    for (int ni = 0; ni < 4; ++ni)
                        acc[mi][ni] = __builtin_amdgcn_mfma_f32_16x16x32_bf16(
                            af[mi], bfr[ni], acc[mi][ni], 0, 0, 0);
            }
            __builtin_amdgcn_s_setprio(0);
        }
        __builtin_amdgcn_s_barrier();
    }

    const int rowb = bx * 128 + wm + q * 4;
    const int colb = by * 128 + wn + rA;

    if (by >= 12) {
        // V -> Vt[b][o][s] via LDS tile [128 o][136 pad s]
        u16* T = smem;
#pragma unroll
        for (int mi = 0; mi < 4; ++mi)
#pragma unroll
            for (int ni = 0; ni < 4; ++ni) {
                const int lc = wn + ni * 16 + rA;
#pragma unroll
                for (int r = 0; r < 4; ++r) {
                    const int lr = wm + mi * 16 + q * 4 + r;
                    T[lc * 136 + lr] = f2bf(acc[mi][ni][r]);
                }
            }
        __syncthreads();
        const int b = bx >> 4;               // 16 x-blocks per batch
        const int s0 = (bx & 15) * 128;
        const int o0 = (by - 12) * 128;
        const int ol = tid >> 1, h = (tid & 1) * 64;
        u16* dst = vt + ((long)b * 768 + o0 + ol) * 2048 + s0 + h;
        const u16* src = &T[ol * 136 + h];
#pragma unroll
        for (int j = 0; j < 8; ++j)
            *(uint4*)(dst + j * 8) = *(const uint4*)(src + j * 8);
        return;
    }

    const int seg = by / 6;                  // 0=Q, 1=K
    const int ocol = colb - seg * 768;
#pragma unroll
    for (int mi = 0; mi < 4; ++mi)
#pragma unroll
        for (int ni = 0; ni < 4; ++ni)
#pragma unroll
            for (int r = 0; r < 4; ++r)
                o16[(long)seg * 6291456 + (long)(rowb + mi * 16 + r) * 768 +
                    ocol + ni * 16] = f2bf(acc[mi][ni][r]);
}

// ---------- shared helpers for bf16 64x128 tiles (PV) ----------
__device__ __forceinline__ void stage_tiles(const u16* Ab, const u16* Bb, int K,
                                            int k0, u16* p, int wave, int rl,
                                            int pc) {
    u16* As = p;
    u16* Bs = p + BM * BK;
#pragma unroll
    for (int t = 0; t < TM; ++t) {
        const int issue = wave + t * 4;
        const int row = issue * 8 + rl;
        const int gc = pc ^ (row & 7);
        gload_lds16(Ab + (long)row * K + k0 + gc * 8, &As[issue * 512]);
    }
#pragma unroll
    for (int t = 0; t < 4; ++t) {
        const int issue = wave + t * 4;
        const int row = issue * 8 + rl;
        const int gc = pc ^ (row & 7);
        gload_lds16(Bb + (long)row * K + k0 + gc * 8, &Bs[issue * 512]);
    }
}

__device__ __forceinline__ void compute_tile(const u16* p, f32x4 (&acc)[TM][4],
                                             int wm, int wn, int q, int rA) {
    const u16* As = p;
    const u16* Bs = p + BM * BK;
#pragma unroll
    for (int kk = 0; kk < BK; kk += 32) {
        const int gchunk = (kk >> 3) + q;
        bf16x8 af[TM], bfr[4];
#pragma unroll
        for (int mi = 0; mi < TM; ++mi) {
            const int R = wm + mi * 16 + rA;
            af[mi] = *(const bf16x8*)&As[R * 64 + ((gchunk ^ (R & 7)) << 3)];
        }
#pragma unroll
        for (int ni = 0; ni < 4; ++ni) {
            const int R = wn + ni * 16 + rA;
            bfr[ni] = *(const bf16x8*)&Bs[R * 64 + ((gchunk ^ (R & 7)) << 3)];
        }
#pragma unroll
        for (int mi = 0; mi < TM; ++mi)
#pragma unroll
            for (int ni = 0; ni < 4; ++ni)
                acc[mi][ni] = __builtin_amdgcn_mfma_f32_16x16x32_bf16(
                    af[mi], bfr[ni], acc[mi][ni], 0, 0, 0);
    }
}

// ---------- PV: 64x128, TRIPLE-buffer counted-vmcnt (K=2048, 32 tiles) -------
__global__ __launch_bounds__(256)
void pv_kernel(const u16* __restrict__ Sb, const u16* __restrict__ Vt,
               float* __restrict__ out, const float* __restrict__ rsum) {
    constexpr int BUF = BM * BK + 128 * BK;              // 12288 u16
    __shared__ __align__(16) u16 smem[3 * BUF];          // 73728 B

    const int nb = gridDim.x;            // 768
    const int chunk = nb >> 3;
    const int nl = (blockIdx.x & 7) * chunk + (blockIdx.x >> 3);
    const int bz = nl / 192;
    const int rem = nl - bz * 192;
    const int bx = rem / 6;
    const int by = rem - bx * 6;

    const int tid = threadIdx.x;
    const int lane = tid & 63;
    const int wave = tid >> 6;

    const u16* Ab = Sb + (long)bz * 4194304L + (long)bx * BM * 2048;
    const u16* Bb = Vt + (long)bz * 1572864L + (long)by * 128 * 2048;

    const int rl = lane >> 3;
    const int pc = lane & 7;
    const int q = lane >> 4;
    const int rA = lane & 15;
    const int wm = (wave >> 1) * 32;
    const int wn = (wave & 1) * 64;

    f32x4 acc[TM][4];
    const f32x4 zero = {0.f, 0.f, 0.f, 0.f};
#pragma unroll
    for (int i = 0; i < TM; i++)
#pragma unroll
        for (int j = 0; j < 4; j++) acc[i][j] = zero;

    u16* p0 = smem;
    u16* p1 = smem + BUF;
    u16* p2 = smem + 2 * BUF;

    const int NT = 32;
    stage_tiles(Ab, Bb, 2048, 0, p0, wave, rl, pc);
    stage_tiles(Ab, Bb, 2048, BK, p1, wave, rl, pc);
    for (int t = 0; t < NT; ++t) {
        if (t + 2 < NT) {
            stage_tiles(Ab, Bb, 2048, (t + 2) * BK, p2, wave, rl, pc);
            asm volatile("s_waitcnt vmcnt(12)" ::: "memory");
        } else if (t + 1 < NT) {
            asm volatile("s_waitcnt vmcnt(6)" ::: "memory");
        } else {
            asm volatile("s_waitcnt vmcnt(0)" ::: "memory");
        }
        __builtin_amdgcn_sched_barrier(0);
        __builtin_amdgcn_s_barrier();
        compute_tile(p0, acc, wm, wn, q, rA);
        __builtin_amdgcn_s_barrier();
        u16* tmp = p0; p0 = p1; p1 = p2; p2 = tmp;
    }

    const int rowb = bx * BM + wm + q * 4;
    const int colb = by * 128 + wn + rA;
    float* dst = out + (long)bz * 1572864L;
#pragma unroll
    for (int mi = 0; mi < TM; ++mi) {
        const float4 rs4 = *(const float4*)&rsum[bz * 2048 + rowb + mi * 16];
        const float inv[4] = {1.f / rs4.x, 1.f / rs4.y, 1.f / rs4.z, 1.f / rs4.w};
#pragma unroll
        for (int ni = 0; ni < 4; ++ni)
#pragma unroll
            for (int r = 0; r < 4; ++r)
                dst[(long)(rowb + mi * 16 + r) * 768 + colb + ni * 16] =
                    acc[mi][ni][r] * inv[r];
    }
}

// ---------- scores: 256x256 tile, 8 waves, counted-vmcnt double-buffer -------
// (Triple-buffer does NOT fit: 3 x 64KB tiles = 192KB > 160KB LDS — round 15.)
__device__ __forceinline__ void sc_stage(const u16* Ab, const u16* Bb, u16* A_,
                                         int t, int w, int rl, int pc) {
    const int k0 = t * 64;
    u16* B_ = A_ + 16384;
#pragma unroll
    for (int j = 0; j < 4; ++j) {
        const int g = w + j * 8;              // wave-uniform, 0..31
        const int row = g * 8 + rl;
        const int gc = pc ^ (row & 7);
        gload_lds16(Ab + (long)row * 768 + k0 + gc * 8, &A_[g * 512]);
    }
#pragma unroll
    for (int j = 0; j < 4; ++j) {
        const int g = w + j * 8;
        const int row = g * 8 + rl;
        const int gc = pc ^ (row & 7);
        gload_lds16(Bb + (long)row * 768 + k0 + gc * 8, &B_[g * 512]);
    }
}

__device__ __forceinline__ void sc_comp(const u16* A_, f32x4 (&acc)[8][4],
                                        int wm, int wn, int q, int rA) {
    const u16* B_ = A_ + 16384;
    __builtin_amdgcn_s_setprio(1);
#pragma unroll
    for (int kk = 0; kk < 64; kk += 32) {
        const int gchunk = (kk >> 3) + q;
        bf16x8 bfr[4];
#pragma unroll
        for (int ni = 0; ni < 4; ++ni) {
            const int R = wn + ni * 16 + rA;
            bfr[ni] = *(const bf16x8*)&B_[R * 64 + ((gchunk ^ (R & 7)) << 3)];
        }
#pragma unroll
        for (int mi = 0; mi < 8; ++mi) {
            const int R = wm + mi * 16 + rA;
            const bf16x8 af = *(const bf16x8*)&A_[R * 64 + ((gchunk ^ (R & 7)) << 3)];
#pragma unroll
            for (int ni = 0; ni < 4; ++ni)
                acc[mi][ni] = __builtin_amdgcn_mfma_f32_16x16x32_bf16(
                    af, bfr[ni], acc[mi][ni], 0, 0, 0);
        }
    }
    __builtin_amdgcn_s_setprio(0);
}

__global__ __launch_bounds__(512, 2)
void scores256_kernel(const u16* __restrict__ Q, const u16* __restrict__ Kb,
                      u16* __restrict__ Sb, float* __restrict__ rsum) {
    __shared__ __align__(16) u16 smem[65536];   // 128 KiB

    const int nb = gridDim.x;                   // 256
    const int chunk = nb >> 3;
    const int nl = (blockIdx.x & 7) * chunk + (blockIdx.x >> 3);
    const int bz = nl >> 6;
    const int rem = nl & 63;
    const int bx = rem >> 3;
    const int by = rem & 7;

    const int tid = threadIdx.x;
    const int lane = tid & 63;
    const int w = tid >> 6;

    const u16* Ab = Q + (long)bz * 1572864L + (long)bx * 256 * 768;
    const u16* Bb = Kb + (long)bz * 1572864L + (long)by * 256 * 768;

    const int rl = lane >> 3, pc = lane & 7;
    const int q = lane >> 4, rA = lane & 15;
    const int wm = (w >> 2) * 128, wn = (w & 3) * 64;

    f32x4 acc[8][4];
    const f32x4 zero = {0.f, 0.f, 0.f, 0.f};
#pragma unroll
    for (int i = 0; i < 8; i++)
#pragma unroll
        for (int j = 0; j < 4; j++) acc[i][j] = zero;

    u16* buf0 = smem;
    u16* buf1 = smem + 32768;

    sc_stage(Ab, Bb, buf0, 0, w, rl, pc);
    for (int i = 0; i < 6; ++i) {
        sc_stage(Ab, Bb, buf1, 2 * i + 1, w, rl, pc);
        asm volatile("s_waitcnt vmcnt(8)" ::: "memory");
        __builtin_amdgcn_sched_barrier(0);
        __builtin_amdgcn_s_barrier();
        sc_comp(buf0, acc, wm, wn, q, rA);
        __builtin_amdgcn_s_barrier();
        if (2 * i + 2 < 12) {
            sc_stage(Ab, Bb, buf0, 2 * i + 2, w, rl, pc);
            asm volatile("s_waitcnt vmcnt(8)" ::: "memory");
        } else {
            asm volatile("s_waitcnt vmcnt(0)" ::: "memory");
        }
        __builtin_amdgcn_sched_barrier(0);
        __builtin_amdgcn_s_barrier();
        sc_comp(buf1, acc, wm, wn, q, rA);
        __builtin_amdgcn_s_barrier();
    }

    const int rowb = bx * 256 + wm + q * 4;
    const int colb = by * 256 + wn + rA;
    u16* dst = Sb + (long)bz * 4194304L;
    const float scale = 0.057735026918962574f;
#pragma unroll
    for (int mi = 0; mi < 8; ++mi) {
        float rs[4] = {0.f, 0.f, 0.f, 0.f};
#pragma unroll
        for (int ni = 0; ni < 4; ++ni)
#pragma unroll
            for (int r = 0; r < 4; ++r) {
                const float p = __expf(acc[mi][ni][r] * scale);
                const u16 pb = f2bf(p);
                dst[(long)(rowb + mi * 16 + r) * 2048 + colb + ni * 16] = pb;
                rs[r] += bf2f(pb);
            }
#pragma unroll
        for (int r = 0; r < 4; ++r) {
#pragma unroll
            for (int off = 1; off <= 8; off <<= 1) rs[r] += __shfl_xor(rs[r], off);
            if (rA == 0)
                atomicAdd(&rsum[bz * 2048 + rowb + mi * 16 + r], rs[r]);
        }
    }
}

extern "C" void kernel_launch(void* const* d_in, const int* in_sizes, int n_in,
                              void* d_out, int out_size, void* d_ws, size_t ws_size,
                              hipStream_t stream) {
    const float* x = (const float*)d_in[0];     // [4,2048,768]
    const float* w = (const float*)d_in[1];     // [3,768,768]
    float* out = (float*)d_out;                 // [4,2048,768]

    const long NX = 6291456L;   // 4*2048*768
    const long NS = 16777216L;  // 4*2048*2048

    u16* Sb = (u16*)d_ws;
    u16* xb = Sb;                 // NX (overlay, dead before scores writes Sb)
    u16* wt = Sb + NX;            // 1769472  (< NS)
    u16* Qb = Sb + NS;
    u16* Kb = Qb + NX;
    u16* Vt = Kb + NX;
    float* rowsum = (float*)(Vt + NX);

    // 1. x -> bf16; W -> Wt[2304][768] bf16 transposed; rowsum <- 0
    cvt_in_kernel<<<7873, 256, 0, stream>>>(x, w, xb, wt, rowsum);
    // 2. QKV: 128x128 counted-vmcnt dbuf; Q,K direct; V transposed into Vt
    qkv_kernel<<<1152, 256, 0, stream>>>(xb, wt, Qb, Vt);
    // 3. P~ = exp(QK^T/sqrt(300)) bf16 -> Sb, + rowsum atomics
    scores256_kernel<<<256, 512, 0, stream>>>(Qb, Kb, Sb, rowsum);
    // 4. out = (P~ x Vt^T) / rowsum -> fp32 (triple-buffer counted-vmcnt)
    pv_kernel<<<768, 256, 0, stream>>>(Sb, Vt, out, rowsum);
}